// Round 14
// baseline (349.934 us; speedup 1.0000x reference)
//
#include <hip/hip_runtime.h>
#include <hip/hip_bf16.h>
#include <math.h>

#define NN 50000
#define NE 800000
#define NEP (NE + NN)   /* edges + self loops */
#define NG 128
#define PSPLIT 16
#define NSB ((NN + 255) / 256)   /* scan blocks = 196 */

typedef unsigned short u16;
typedef __bf16 bf16x8 __attribute__((ext_vector_type(8)));
typedef float f32x4 __attribute__((ext_vector_type(4)));

#define L2E 1.4426950408889634f

__device__ __forceinline__ float eluf(float v) {
  return v > 0.0f ? v : expm1f(v);
}
__device__ __forceinline__ float bflo(unsigned u) {
  union { unsigned i; float f; } c; c.i = u << 16; return c.f;
}
__device__ __forceinline__ float bfhi(unsigned u) {
  union { unsigned i; float f; } c; c.i = u & 0xffff0000u; return c.f;
}
__device__ __forceinline__ bf16x8 load8(const u16* p) {
  union { uint4 u; bf16x8 v; } c;
  c.u = *(const uint4*)p;
  return c.v;
}
__device__ __forceinline__ void unpack8(uint4 u, float* xv) {
  xv[0] = bflo(u.x); xv[1] = bfhi(u.x);
  xv[2] = bflo(u.y); xv[3] = bfhi(u.y);
  xv[4] = bflo(u.z); xv[5] = bfhi(u.z);
  xv[6] = bflo(u.w); xv[7] = bfhi(u.w);
}

__global__ __launch_bounds__(256) void k_deg(const int* __restrict__ ei, int* __restrict__ deg) {
  int t = blockIdx.x * 256 + threadIdx.x;
  if (t >= NEP) return;
  int dst = (t < NE) ? ei[NE + t] : (t - NE);
  atomicAdd(&deg[dst], 1);
}

// ---- multi-block exclusive scan of deg -> rowptr ----
__global__ __launch_bounds__(256) void k_scan1(const int* __restrict__ deg, int* __restrict__ bsum) {
  __shared__ int red[256];
  int i = blockIdx.x * 256 + threadIdx.x;
  red[threadIdx.x] = (i < NN) ? deg[i] : 0;
  __syncthreads();
  for (int off = 128; off > 0; off >>= 1) {
    if (threadIdx.x < off) red[threadIdx.x] += red[threadIdx.x + off];
    __syncthreads();
  }
  if (threadIdx.x == 0) bsum[blockIdx.x] = red[0];
}

__global__ __launch_bounds__(256) void k_scan2(int* __restrict__ bsum) {
  __shared__ int s[256];
  int t = threadIdx.x;
  s[t] = (t < NSB) ? bsum[t] : 0;
  __syncthreads();
  for (int off = 1; off < 256; off <<= 1) {
    int v = (t >= off) ? s[t - off] : 0;
    __syncthreads();
    s[t] += v;
    __syncthreads();
  }
  if (t < NSB) bsum[t] = (t == 0) ? 0 : s[t - 1];
}

__global__ __launch_bounds__(256) void k_scan3(const int* __restrict__ deg, const int* __restrict__ bsum,
                                               int* __restrict__ rowptr) {
  __shared__ int s[256];
  int t = threadIdx.x;
  int i = blockIdx.x * 256 + t;
  s[t] = (i < NN) ? deg[i] : 0;
  __syncthreads();
  for (int off = 1; off < 256; off <<= 1) {
    int v = (t >= off) ? s[t - off] : 0;
    __syncthreads();
    s[t] += v;
    __syncthreads();
  }
  int excl = (t == 0) ? 0 : s[t - 1];
  if (i <= NN) rowptr[i] = bsum[blockIdx.x] + excl;
}

__global__ __launch_bounds__(256) void k_scatter(const int* __restrict__ ei, const int* __restrict__ rowptr,
                                                 int* __restrict__ fill, int* __restrict__ srcidx) {
  int t = blockIdx.x * 256 + threadIdx.x;
  if (t >= NEP) return;
  int src, dst;
  if (t < NE) { src = ei[t]; dst = ei[NE + t]; } else { src = t - NE; dst = src; }
  int pos = atomicAdd(&fill[dst], 1);
  srcidx[rowptr[dst] + pos] = src;
}

__global__ __launch_bounds__(256) void k_cvtw(const float* __restrict__ w1, const float* __restrict__ w2,
                                              const float* __restrict__ w3, const float* __restrict__ w4,
                                              u16* __restrict__ o) {
  int t = blockIdx.x * 256 + threadIdx.x;
  if (t >= 81920) return;
  float v;
  if (t < 8192) v = w1[t];
  else if (t < 16384) v = w2[t - 8192];
  else if (t < 49152) v = w3[t - 16384];
  else v = w4[t - 49152];
  __hip_bfloat16 b = __float2bfloat16(v);
  o[t] = *(u16*)&b;
}

// ---- MFMA dual GEMM: Y = X@W^T + bias, W picked by blockIdx.z (l: bf16 out, r: f32 out)
// No LDS: fragments loaded directly from L2/L3-resident tables (m89 layouts).
// AF32: A operand read as f32 and converted inline (saves the separate cvt pass;
// identical RNE rounding to the old k_cvtx).
template <int K, bool AF32>
__global__ __launch_bounds__(256) void k_mfma(const void* __restrict__ Xin,
                                              const u16* __restrict__ Wlb, const u16* __restrict__ Wrb,
                                              const float* __restrict__ bl, const float* __restrict__ br,
                                              __hip_bfloat16* __restrict__ Yl, float* __restrict__ Yr,
                                              int dout) {
  int lane = threadIdx.x & 63;
  int wid = threadIdx.x >> 6;
  int r0 = blockIdx.x * 64 + wid * 16;
  int c0 = blockIdx.y * 64;
  bool isR = (blockIdx.z != 0);
  const u16* W = isR ? Wrb : Wlb;
  const float* bias = isR ? br : bl;

  int arow = min(r0 + (lane & 15), NN - 1);
  int koff = (lane >> 4) * 8;
  const u16*   aph = (const u16*)Xin + (size_t)arow * K + koff;
  const float* apf = (const float*)Xin + (size_t)arow * K + koff;
  const u16* bp = W + (size_t)(c0 + (lane & 15)) * K + koff;

  f32x4 acc[4] = {};
#pragma unroll
  for (int ks = 0; ks < K / 32; ++ks) {
    bf16x8 a;
    if constexpr (AF32) {
      float4 f0 = ((const float4*)(apf + ks * 32))[0];
      float4 f1 = ((const float4*)(apf + ks * 32))[1];
      a[0] = (__bf16)f0.x; a[1] = (__bf16)f0.y; a[2] = (__bf16)f0.z; a[3] = (__bf16)f0.w;
      a[4] = (__bf16)f1.x; a[5] = (__bf16)f1.y; a[6] = (__bf16)f1.z; a[7] = (__bf16)f1.w;
    } else {
      a = load8(aph + ks * 32);
    }
    bf16x8 b0 = load8(bp + ks * 32);
    bf16x8 b1 = load8(bp + 16 * K + ks * 32);
    bf16x8 b2 = load8(bp + 32 * K + ks * 32);
    bf16x8 b3 = load8(bp + 48 * K + ks * 32);
    acc[0] = __builtin_amdgcn_mfma_f32_16x16x32_bf16(a, b0, acc[0], 0, 0, 0);
    acc[1] = __builtin_amdgcn_mfma_f32_16x16x32_bf16(a, b1, acc[1], 0, 0, 0);
    acc[2] = __builtin_amdgcn_mfma_f32_16x16x32_bf16(a, b2, acc[2], 0, 0, 0);
    acc[3] = __builtin_amdgcn_mfma_f32_16x16x32_bf16(a, b3, acc[3], 0, 0, 0);
  }

  int orow = r0 + ((lane >> 4) << 2);
  int ocol = c0 + (lane & 15);
#pragma unroll
  for (int t = 0; t < 4; ++t) {
    int col = ocol + t * 16;
    float bv = bias[col];
    if (!isR) {
#pragma unroll
      for (int v = 0; v < 4; ++v) {
        int row = orow + v;
        if (row < NN) Yl[(size_t)row * dout + col] = __float2bfloat16(acc[t][v] + bv);
      }
    } else {
#pragma unroll
      for (int v = 0; v < 4; ++v) {
        int row = orow + v;
        if (row < NN) Yr[(size_t)row * dout + col] = acc[t][v] + bv;
      }
    }
  }
}

// ---- fused GATv2 edge-score + softmax + aggregation ----
// C = channels/head (32 L1, 64 L2); D = 4C. Lane owns 8 channels (V=8):
// LPE = D/8 lanes per edge, EPW = 64/LPE edges per wave-instruction (4 L1, 2 L2),
// HL = C/8 lanes per head -> reduce tree log2(HL) steps serving EPW edges at once.
// Factored score, single accumulator:
//   lrelu(u) = 0.6u + 0.4|u|; attv = 0.4*log2e*att:
//   score*log2e = sum_c attv*(|u| + 1.5*xl) + S0,  S0 = 1.5*sum_c attv*xr  (per head)
// |u| is a free VOP3 modifier; exp via raw v_exp_f32 (scores bounded ~ +-10).
// Fixed-shift softmax (m=0) - shift-invariant. Phantom tail edges get w=0.
template <int C, bool OBF16>
__global__ __launch_bounds__(256) void k_fused(const int* __restrict__ rowptr, const int* __restrict__ srcidx,
                                               const u16* __restrict__ xl, const float* __restrict__ xr,
                                               const float* __restrict__ att, const float* __restrict__ bias,
                                               void* __restrict__ outv) {
  constexpr int D = 4 * C, LPE = D / 8, EPW = 64 / LPE, HL = C / 8;
  int lane = threadIdx.x & 63;
  int node = blockIdx.x * 4 + (threadIdx.x >> 6);
  if (node >= NN) return;
  int il = lane % LPE, sub = lane / LPE;
  int lo = rowptr[node], hi = rowptr[node + 1];

  float xrv[8], attv[8];
  float rpart = 0.f;
#pragma unroll
  for (int q = 0; q < 8; ++q) {
    attv[q] = att[il * 8 + q] * (0.4f * L2E);
    xrv[q]  = xr[(size_t)node * D + il * 8 + q];
    rpart = fmaf(attv[q], xrv[q], rpart);
  }
#pragma unroll
  for (int off = 1; off < HL; off <<= 1) rpart += __shfl_xor(rpart, off);
  float S0 = 1.5f * rpart;

  const uint4* xt = (const uint4*)xl;
  float denom = 0.f;
  float acc[8] = {};

  auto score1 = [&](const float* xv) {
    float p = 0.f;
#pragma unroll
    for (int q = 0; q < 8; ++q) {
      float u = xv[q] + xrv[q];
      float t = fmaf(1.5f, xv[q], fabsf(u));
      p = fmaf(attv[q], t, p);
    }
    return p;
  };

  int s0 = lo;
  for (; s0 + 2 * EPW <= hi; s0 += 2 * EPW) {
    int j0 = srcidx[s0 + sub];
    int j1 = srcidx[s0 + EPW + sub];
    uint4 u0 = xt[(size_t)j0 * LPE + il];
    uint4 u1 = xt[(size_t)j1 * LPE + il];
    float xv0[8], xv1[8];
    unpack8(u0, xv0); unpack8(u1, xv1);
    float p0 = score1(xv0);
    float p1 = score1(xv1);
#pragma unroll
    for (int off = 1; off < HL; off <<= 1) {
      p0 += __shfl_xor(p0, off);
      p1 += __shfl_xor(p1, off);
    }
    float w0 = __builtin_amdgcn_exp2f(p0 + S0);
    float w1 = __builtin_amdgcn_exp2f(p1 + S0);
    denom += w0 + w1;
#pragma unroll
    for (int q = 0; q < 8; ++q) acc[q] = fmaf(w1, xv1[q], fmaf(w0, xv0[q], acc[q]));
  }
  for (; s0 < hi; s0 += EPW) {
    int e = s0 + sub;
    bool valid = e < hi;
    int j = srcidx[valid ? e : lo];
    uint4 u = xt[(size_t)j * LPE + il];
    float xv[8];
    unpack8(u, xv);
    float p = score1(xv);
#pragma unroll
    for (int off = 1; off < HL; off <<= 1) p += __shfl_xor(p, off);
    float w = valid ? __builtin_amdgcn_exp2f(p + S0) : 0.f;
    denom += w;
#pragma unroll
    for (int q = 0; q < 8; ++q) acc[q] = fmaf(w, xv[q], acc[q]);
  }

  // combine edge sub-groups
#pragma unroll
  for (int off = LPE; off < 64; off <<= 1) {
    denom += __shfl_xor(denom, off);
#pragma unroll
    for (int q = 0; q < 8; ++q) acc[q] += __shfl_xor(acc[q], off);
  }

  if (sub == 0) {
    float rd = 1.0f / denom;
    float vals[8];
#pragma unroll
    for (int q = 0; q < 8; ++q) vals[q] = eluf(fmaf(acc[q], rd, bias[il * 8 + q]));
    if constexpr (OBF16) {
      __hip_bfloat16 tmp[8];
#pragma unroll
      for (int q = 0; q < 8; ++q) tmp[q] = __float2bfloat16(vals[q]);
      ((uint4*)outv)[(size_t)node * LPE + il] = *(uint4*)tmp;
    } else {
      float4 f0 = {vals[0], vals[1], vals[2], vals[3]};
      float4 f1 = {vals[4], vals[5], vals[6], vals[7]};
      ((float4*)outv)[(size_t)node * (D / 4) + il * 2]     = f0;
      ((float4*)outv)[(size_t)node * (D / 4) + il * 2 + 1] = f1;
    }
  }
}

__device__ __forceinline__ int lowerb(const int* __restrict__ a, int n, int v) {
  int lo = 0, hi = n;
  while (lo < hi) { int mid = (lo + hi) >> 1; if (a[mid] < v) lo = mid + 1; else hi = mid; }
  return lo;
}

// ---- two-stage mean pool ----
__global__ __launch_bounds__(256) void k_pool(const float* __restrict__ h2, const int* __restrict__ batch,
                                              float* __restrict__ pooled_p) {
  int g = blockIdx.x, sp = blockIdx.y, t = threadIdx.x;
  __shared__ int sh[2];
  if (t < 2) sh[t] = lowerb(batch, NN, g + t);
  __syncthreads();
  int lo = sh[0], hi = sh[1];
  int cnt = hi - lo;
  int chunk = (cnt + PSPLIT - 1) / PSPLIT;
  int b = lo + sp * chunk;
  int e = min(b + chunk, hi);
  float acc = 0.f;
  for (int n = b; n < e; ++n) acc += h2[(size_t)n * 256 + t];
  pooled_p[((size_t)g * PSPLIT + sp) * 256 + t] = acc;
}

__global__ __launch_bounds__(128) void k_cls(const float* __restrict__ pooled_p, const int* __restrict__ batch,
                                             const float* __restrict__ Wf1, const float* __restrict__ bf1,
                                             const float* __restrict__ Wf2, const float* __restrict__ bf2,
                                             float* __restrict__ out) {
  __shared__ float p[256];
  __shared__ float z[128];
  __shared__ int sh[2];
  int g = blockIdx.x, t = threadIdx.x;
  if (t < 2) sh[t] = lowerb(batch, NN, g + t);
  __syncthreads();
  float cnt = (float)(sh[1] - sh[0]);
  float rinv = 1.0f / fmaxf(cnt, 1.0f);
  const float* pp = pooled_p + (size_t)g * PSPLIT * 256;
#pragma unroll 1
  for (int c = t; c < 256; c += 128) {
    float s = 0.f;
#pragma unroll
    for (int sp = 0; sp < PSPLIT; ++sp) s += pp[sp * 256 + c];
    p[c] = s * rinv;
  }
  __syncthreads();
  float a = bf1[t];
  const float* wr = Wf1 + (size_t)t * 256;
  for (int k = 0; k < 256; ++k) a += p[k] * wr[k];
  z[t] = fmaxf(a, 0.f);
  __syncthreads();
  if (t < 8) {
    float o = bf2[t];
    const float* w2 = Wf2 + t * 128;
    for (int k = 0; k < 128; ++k) o += z[k] * w2[k];
    out[g * 8 + t] = o;
  }
}

extern "C" void kernel_launch(void* const* d_in, const int* in_sizes, int n_in,
                              void* d_out, int out_size, void* d_ws, size_t ws_size,
                              hipStream_t stream) {
  const float* x     = (const float*)d_in[0];
  const int*   ei    = (const int*)d_in[1];
  const int*   batch = (const int*)d_in[2];
  const float* Wl1 = (const float*)d_in[3];
  const float* bl1 = (const float*)d_in[4];
  const float* Wr1 = (const float*)d_in[5];
  const float* br1 = (const float*)d_in[6];
  const float* att1  = (const float*)d_in[7];
  const float* bias1 = (const float*)d_in[8];
  const float* Wl2 = (const float*)d_in[9];
  const float* bl2 = (const float*)d_in[10];
  const float* Wr2 = (const float*)d_in[11];
  const float* br2 = (const float*)d_in[12];
  const float* att2  = (const float*)d_in[13];
  const float* bias2 = (const float*)d_in[14];
  const float* Wf1 = (const float*)d_in[15];
  const float* bf1 = (const float*)d_in[16];
  const float* Wf2 = (const float*)d_in[17];
  const float* bf2 = (const float*)d_in[18];
  float* out = (float*)d_out;

  char* w = (char*)d_ws;
  size_t off = 0;
  auto alloc = [&](size_t bytes) -> void* {
    void* p = w + off;
    off += (bytes + 255) & ~(size_t)255;
    return p;
  };
  int* rowptr = (int*)alloc((NN + 1) * sizeof(int));
  int* deg    = (int*)alloc(NN * sizeof(int));
  int* fill   = (int*)alloc(NN * sizeof(int));
  int* bsum   = (int*)alloc(NSB * sizeof(int));
  int* srcidx = (int*)alloc((size_t)NEP * sizeof(int));
  u16* Wb     = (u16*)alloc((size_t)81920 * sizeof(u16));       // all 4 W in bf16
  u16* Wl1b = Wb, *Wr1b = Wb + 8192, *Wl2b = Wb + 16384, *Wr2b = Wb + 49152;
  // region A: xl1(bf16 12.8MB) + xr1(f32 25.6MB), later reused for xl2(bf16 25.6MB)
  char* regA  = (char*)alloc((size_t)NN * 128 * 2 + (size_t)NN * 128 * 4);
  __hip_bfloat16* xl1 = (__hip_bfloat16*)regA;
  float*          xr1 = (float*)(regA + (size_t)NN * 128 * 2);
  __hip_bfloat16* xl2 = (__hip_bfloat16*)regA;          // overlays xl1+xr1 (dead by then)
  u16*   h1b    = (u16*)alloc((size_t)NN * 128 * sizeof(u16)); // h1 in bf16 (layer-2 A)
  float* xr2    = (float*)alloc((size_t)NN * 256 * sizeof(float));
  float* h2     = xr2;   // in-place: each node reads its xr row before writing
  float* pooled_p = (float*)alloc((size_t)NG * PSPLIT * 256 * sizeof(float));
  (void)ws_size; (void)in_sizes; (void)n_in; (void)out_size;

  hipMemsetAsync(deg, 0, NN * sizeof(int), stream);
  hipMemsetAsync(fill, 0, NN * sizeof(int), stream);

  const int EB = (NEP + 255) / 256;
  k_deg<<<EB, 256, 0, stream>>>(ei, deg);
  k_scan1<<<NSB, 256, 0, stream>>>(deg, bsum);
  k_scan2<<<1, 256, 0, stream>>>(bsum);
  k_scan3<<<NSB, 256, 0, stream>>>(deg, bsum, rowptr);
  k_scatter<<<EB, 256, 0, stream>>>(ei, rowptr, fill, srcidx);

  k_cvtw<<<(81920 + 255) / 256, 256, 0, stream>>>(Wl1, Wr1, Wl2, Wr2, Wb);

  const int RB = (NN + 63) / 64;
  // ---- layer 1 (64 -> 4x32) ----
  dim3 g1(RB, 2, 2);
  k_mfma<64, true><<<g1, 256, 0, stream>>>(x, Wl1b, Wr1b, bl1, br1, xl1, xr1, 128);
  k_fused<32, true><<<(NN + 3) / 4, 256, 0, stream>>>(rowptr, srcidx, (const u16*)xl1, xr1,
                                                      att1, bias1, h1b);

  // ---- layer 2 (128 -> 4x64) ----
  dim3 g2(RB, 4, 2);
  k_mfma<128, false><<<g2, 256, 0, stream>>>(h1b, Wl2b, Wr2b, bl2, br2, xl2, xr2, 256);
  k_fused<64, false><<<(NN + 3) / 4, 256, 0, stream>>>(rowptr, srcidx, (const u16*)xl2, xr2,
                                                       att2, bias2, h2);

  // ---- pool + classifier ----
  dim3 gp(NG, PSPLIT);
  k_pool<<<gp, 256, 0, stream>>>(h2, batch, pooled_p);
  k_cls<<<NG, 128, 0, stream>>>(pooled_p, batch, Wf1, bf1, Wf2, bf2, out);
}